// Round 12
// baseline (754.702 us; speedup 1.0000x reference)
//
#include <hip/hip_runtime.h>
#include <math.h>

// ---------------- problem constants ----------------
#define BATCH 32768
#define HID   512
#define NOBJ  5
#define TM    128           // batch rows per block (MFMA path), 512 threads
#define NBT   (BATCH/TM)    // 256 batch tiles

typedef __attribute__((ext_vector_type(8))) short bf16x8;
typedef __attribute__((ext_vector_type(4))) float f32x4;

__device__ __constant__ int d_OIDS[5][12] = {
  {0,1,2,3, 10,11,12,13,14,18,22,26},
  {0,4,5,6, 10,14,15,16,17,19,23,27},
  {1,4,7,8, 11,15,18,19,20,21,24,28},
  {2,5,7,9, 12,16,20,22,23,24,25,29},
  {3,6,8,9, 13,17,21,25,26,27,28,29}
};

// ---------------- bf16 weight workspace (ushort offsets) ----------------
#define UO_EW0   0                       // [512][64]  (K padded 44->64)
#define UO_EW1   (UO_EW0 + 512*64)       // [512][512]
#define UO_HEADS (UO_EW1 + 512*512)      // [32][512]: rows 0-8 Wm, 16-24 Wv, rest 0
#define UO_DW0   (UO_HEADS + 32*512)     // [512][64]  (K padded 41->64)
#define UO_DW1   (UO_DW0 + 512*64)       // [512][512]
#define UO_DW2   (UO_DW1 + 512*512)      // [16][512]: rows 0-11 dec_W2, rest 0
#define UO_TOTAL (UO_DW2 + 16*512)       // 614400 ushorts = 1.23 MB

// ---------------- output layout (floats) ----------------
#define OUT_MEANS (BATCH*30)
#define OUT_LV    (OUT_MEANS + NOBJ*BATCH*9)
#define OUT_Z     (OUT_LV    + NOBJ*BATCH*9)

// round-to-nearest-even f32 -> bf16 bits
__device__ __forceinline__ unsigned short f2b(float x) {
  unsigned int u = __builtin_bit_cast(unsigned int, x);
  u += 0x7FFFu + ((u >> 16) & 1u);
  return (unsigned short)(u >> 16);
}

// ---------------- prep: convert/pad weights into ws (bf16) ----------------
__global__ void __launch_bounds__(256)
prep_bf16(const float* __restrict__ eW0, const float* __restrict__ eW1,
          const float* __restrict__ Wm,  const float* __restrict__ Wv,
          const float* __restrict__ dW0, const float* __restrict__ dW1,
          const float* __restrict__ dW2, unsigned short* __restrict__ ws)
{
  for (int i = blockIdx.x*blockDim.x + threadIdx.x; i < UO_TOTAL; i += gridDim.x*blockDim.x) {
    float v = 0.f; int j;
    if (i < UO_EW1) {                       // [512][64] <- eW0 [512][44]
      j = i - UO_EW0; int h = j >> 6, k = j & 63;
      if (k < 44) v = eW0[h*44 + k];
    } else if (i < UO_HEADS) {              // [512][512] <- eW1
      j = i - UO_EW1; v = eW1[j];
    } else if (i < UO_DW0) {                // [32][512] heads
      j = i - UO_HEADS; int r = j >> 9, k = j & 511;
      if (r < 9)                  v = Wm[r*512 + k];
      else if (r >= 16 && r < 25) v = Wv[(r-16)*512 + k];
    } else if (i < UO_DW1) {                // [512][64] <- dW0 [512][41]
      j = i - UO_DW0; int h = j >> 6, k = j & 63;
      if (k < 41) v = dW0[h*41 + k];
    } else if (i < UO_DW2) {                // [512][512] <- dW1
      j = i - UO_DW1; v = dW1[j];
    } else {                                // [16][512] <- dW2 [12][512]
      j = i - UO_DW2; int r = j >> 9, k = j & 511;
      if (r < 12) v = dW2[r*512 + k];
    }
    ws[i] = f2b(v);
  }
}

// One dense layer: out[128][512] = relu(in[128][K] * W^T + bias).
// 8 waves, 1M x 8N: wave covers ALL 128 rows (8 M-tiles) x cols [wave*64,+64)
// (4 N-tiles): acc[8][4] = 128 AGPR. Per kt: 4 B global loads (ping-pong),
// 8 A ds_reads (direct), 32 MFMA -> 8:1 MFMA:B-load. NO barriers in K-loop;
// waves run K unsynchronized. Register budget (2 waves/SIMD = 256/wave):
// 128 acc + 32 b + 32 a + ~40 addr/misc ~ 232 < 256 -> no spill.
// In-place (sIn==sOut) safe: epilogue barrier precedes writes.
template<int KT, int ROWW>   // K = KT*32, KT even
__device__ __forceinline__ void layer_mfma(const unsigned short* sIn,
                                           const unsigned short* __restrict__ Wb,
                                           const float* __restrict__ bias,
                                           unsigned short* sOut,
                                           int wave, int lane)
{
  const int lcol = lane & 15;
  const int kg   = lane >> 4;
  const int lk   = kg * 8;
  const int colbase = wave * 64;
  const int swz = (lcol & 7) << 3;     // rows m*16+lcol: row&7 == lcol&7

  f32x4 acc[8][4];
  #pragma unroll
  for (int n = 0; n < 4; ++n) {
    const float bv = bias[colbase + n*16 + lcol];
    #pragma unroll
    for (int m = 0; m < 8; ++m) acc[m][n] = (f32x4){bv, bv, bv, bv};
  }

  const unsigned short* wpn[4];
  #pragma unroll
  for (int n = 0; n < 4; ++n)
    wpn[n] = Wb + (size_t)(colbase + n*16 + lcol)*(KT*32) + lk;

  bf16x8 b0[4], b1[4], a[8];
  #pragma unroll
  for (int n = 0; n < 4; ++n) b0[n] = *(const bf16x8*)(wpn[n]);
  #pragma unroll
  for (int n = 0; n < 4; ++n) b1[n] = *(const bf16x8*)(wpn[n] + 32);

  #pragma unroll 1
  for (int kt = 0; kt < KT; kt += 2) {
    {
      const int k0 = kt*32 + lk;
      #pragma unroll
      for (int m = 0; m < 8; ++m)
        a[m] = *(const bf16x8*)&sIn[(m*16 + lcol)*ROWW + (k0 ^ swz)];
      #pragma unroll
      for (int n = 0; n < 4; ++n)
        #pragma unroll
        for (int m = 0; m < 8; ++m)
          acc[m][n] = __builtin_amdgcn_mfma_f32_16x16x32_bf16(a[m], b0[n], acc[m][n], 0, 0, 0);
    }
    if (kt + 2 < KT) {                   // prefetch B(kt+2)
      #pragma unroll
      for (int n = 0; n < 4; ++n) b0[n] = *(const bf16x8*)(wpn[n] + (kt+2)*32);
    }
    {
      const int k1 = (kt+1)*32 + lk;
      #pragma unroll
      for (int m = 0; m < 8; ++m)
        a[m] = *(const bf16x8*)&sIn[(m*16 + lcol)*ROWW + (k1 ^ swz)];
      #pragma unroll
      for (int n = 0; n < 4; ++n)
        #pragma unroll
        for (int m = 0; m < 8; ++m)
          acc[m][n] = __builtin_amdgcn_mfma_f32_16x16x32_bf16(a[m], b1[n], acc[m][n], 0, 0, 0);
    }
    if (kt + 3 < KT) {                   // prefetch B(kt+3)
      #pragma unroll
      for (int n = 0; n < 4; ++n) b1[n] = *(const bf16x8*)(wpn[n] + (kt+3)*32);
    }
  }

  __syncthreads();   // all reads of sIn done before (possibly aliased) writes
  const int rbase = kg * 4;
  #pragma unroll
  for (int m = 0; m < 8; ++m)
    #pragma unroll
    for (int n = 0; n < 4; ++n) {
      const int col = colbase + n*16 + lcol;
      #pragma unroll
      for (int r = 0; r < 4; ++r) {
        const int row = m*16 + rbase + r;
        sOut[row*512 + (col ^ ((row & 7) << 3))] = f2b(fmaxf(acc[m][n][r], 0.f));
      }
    }
  __syncthreads();
}

// grid = NOBJ * NBT blocks; block = one (object, 128-row batch tile).
__global__ void __launch_bounds__(512, 2)
vae_mfma(const float* __restrict__ initial_c, const float* __restrict__ initial_s,
         const float* __restrict__ current_c, const float* __restrict__ eps,
         const float* __restrict__ enc_b0, const float* __restrict__ enc_b1,
         const float* __restrict__ bm, const float* __restrict__ bv,
         const float* __restrict__ dec_b0, const float* __restrict__ dec_b1,
         const float* __restrict__ dec_b2, const unsigned short* __restrict__ ws,
         float* __restrict__ out)
{
  __shared__ __align__(16) unsigned short s_act[TM*512];   // 128 KB activations
  __shared__ __align__(16) unsigned short s_in[TM*64];     // 16 KB enc/dec input
  __shared__ float s_stage[3*TM*9];                        // 13.5 KB head f32 stage
  // 157.5 KB -> 1 block/CU, 8 waves (2/SIMD, 256 regs each)

  const int t = threadIdx.x;
  const int wave = t >> 6, lane = t & 63;
  const int lcol = lane & 15, kg = lane >> 4;
  const int lk = kg * 8, rbase = kg * 4;
  const int o     = blockIdx.x / NBT;
  const int bbase = (blockIdx.x % NBT) * TM;

  // ---- encoder input [128][64]: [oh 0-4 | s 5-19 | gi 20-31 | gc 32-43 | 0] ----
  for (int s = t; s < TM*64; s += 512) {
    const int row = s >> 6, col = s & 63;
    float v = 0.f;
    if (col < 5)       v = (col == o) ? 1.f : 0.f;
    else if (col < 20) v = initial_s[(bbase+row)*15 + col - 5];
    else if (col < 32) v = initial_c[(bbase+row)*30 + d_OIDS[o][col-20]];
    else if (col < 44) v = current_c[(bbase+row)*30 + d_OIDS[o][col-32]];
    s_in[row*64 + (col ^ ((row & 7) << 3))] = f2b(v);
  }
  __syncthreads();

  layer_mfma<2, 64>  (s_in,  ws + UO_EW0, enc_b0, s_act, wave, lane);  // h1
  layer_mfma<16, 512>(s_act, ws + UO_EW1, enc_b1, s_act, wave, lane);  // h2

  // ---- heads: means / log_var / z (each wave owns rows [wave*16,+16)) ----
  {
    // decoder input (non-z cols): [oh 0-4 | z 5-13 | s 14-28 | gi 29-40 | 0]
    // (s_in fully consumed by h1; safe to rebuild concurrently with head MFMA)
    for (int s = t; s < TM*64; s += 512) {
      const int row = s >> 6, col = s & 63;
      if (col >= 5 && col < 14) continue;
      float v = 0.f;
      if (col < 5)       v = (col == o) ? 1.f : 0.f;
      else if (col < 29) v = initial_s[(bbase+row)*15 + col - 14];
      else if (col < 41) v = initial_c[(bbase+row)*30 + d_OIDS[o][col-29]];
      s_in[row*64 + (col ^ ((row & 7) << 3))] = f2b(v);
    }
    f32x4 am, av;
    {
      const float bmv = (lcol < 9) ? bm[lcol] : 0.f;
      const float bvv = (lcol < 9) ? bv[lcol] : 0.f;
      am = (f32x4){bmv, bmv, bmv, bmv};
      av = (f32x4){bvv, bvv, bvv, bvv};
      const unsigned short* hpM = ws + UO_HEADS + lcol*512 + lk;
      const unsigned short* hpV = hpM + 16*512;
      const int hrow = wave*16 + lcol;
      bf16x8 m0 = *(const bf16x8*)hpM;
      bf16x8 v0 = *(const bf16x8*)hpV;
      #pragma unroll 1
      for (int kt = 0; kt < 16; ++kt) {
        bf16x8 m1 = m0, v1 = v0;
        if (kt + 1 < 16) {               // register ping-pong prefetch
          m1 = *(const bf16x8*)(hpM + (kt+1)*32);
          v1 = *(const bf16x8*)(hpV + (kt+1)*32);
        }
        const int k0 = kt*32 + lk;
        bf16x8 a = *(const bf16x8*)&s_act[hrow*512 + (k0 ^ ((lcol & 7) << 3))];
        am = __builtin_amdgcn_mfma_f32_16x16x32_bf16(a, m0, am, 0, 0, 0);
        av = __builtin_amdgcn_mfma_f32_16x16x32_bf16(a, v0, av, 0, 0, 0);
        m0 = m1; v0 = v1;
      }
    }
    __syncthreads();   // all head reads of h2 done
    if (lcol < 9) {
      #pragma unroll
      for (int r = 0; r < 4; ++r) {
        const int row = wave*16 + rbase + r;
        const int gid = (o*BATCH + bbase + row)*9 + lcol;
        const float m_ = am[r], v_ = av[r];
        const float zz = fmaf(eps[gid], expf(0.5f*v_), m_);
        s_stage[        row*9 + lcol] = m_;
        s_stage[1152 +  row*9 + lcol] = v_;
        s_stage[2304 +  row*9 + lcol] = zz;
        s_in[row*64 + ((5 + lcol) ^ ((row & 7) << 3))] = f2b(zz);
      }
    }
    __syncthreads();
    // coalesced nontemporal head-output writes (contiguous 4.6 KB each)
    const int ob_m = OUT_MEANS + (o*BATCH + bbase)*9;
    const int ob_v = OUT_LV    + (o*BATCH + bbase)*9;
    const int ob_z = OUT_Z     + (o*BATCH + bbase)*9;
    for (int i = t; i < TM*9; i += 512) {
      __builtin_nontemporal_store(s_stage[i],        &out[ob_m + i]);
      __builtin_nontemporal_store(s_stage[1152 + i], &out[ob_v + i]);
      __builtin_nontemporal_store(s_stage[2304 + i], &out[ob_z + i]);
    }
  }

  layer_mfma<2, 64>  (s_in,  ws + UO_DW0, dec_b0, s_act, wave, lane);  // g1
  layer_mfma<16, 512>(s_act, ws + UO_DW1, dec_b1, s_act, wave, lane);  // g2

  // ---- dec head: sigmoid + atomic scatter (exactly 2 commutative adds/elem) ----
  {
    const float b2 = (lcol < 12) ? dec_b2[lcol] : 0.f;
    f32x4 acc = (f32x4){b2, b2, b2, b2};
    const unsigned short* wp = ws + UO_DW2 + lcol*512 + lk;
    const int hrow = wave*16 + lcol;
    bf16x8 b0 = *(const bf16x8*)wp;
    #pragma unroll 1
    for (int kt = 0; kt < 16; ++kt) {
      bf16x8 b1 = b0;
      if (kt + 1 < 16) b1 = *(const bf16x8*)(wp + (kt+1)*32);
      const int k0 = kt*32 + lk;
      bf16x8 a = *(const bf16x8*)&s_act[hrow*512 + (k0 ^ ((lcol & 7) << 3))];
      acc = __builtin_amdgcn_mfma_f32_16x16x32_bf16(a, b0, acc, 0, 0, 0);
      b0 = b1;
    }
    if (lcol < 12) {
      const int c30 = d_OIDS[o][lcol];
      #pragma unroll
      for (int r = 0; r < 4; ++r) {
        const int row = wave*16 + rbase + r;
        atomicAdd(&out[(bbase + row)*30 + c30], 1.f / (1.f + expf(-acc[r])));
      }
    }
  }
}

// ---------------- fallback (ws too small): correct but slow fp32 ----------------
__global__ void __launch_bounds__(256)
vae_naive(const float* __restrict__ initial_c, const float* __restrict__ initial_s,
          const float* __restrict__ current_c, const float* __restrict__ eps,
          const float* eW0, const float* eb0, const float* eW1, const float* eb1,
          const float* Wm, const float* bm, const float* Wv, const float* bv,
          const float* dW0, const float* db0, const float* dW1, const float* db1,
          const float* dW2, const float* db2, float* out)
{
  __shared__ float xs[44], ds[41], h1[HID], h2[HID], rec[30];
  const int b = blockIdx.x, t = threadIdx.x;
  if (t < 30) rec[t] = 0.f;
  for (int o = 0; o < NOBJ; ++o) {
    __syncthreads();
    if (t < 44) {
      float v;
      if      (t < 5)  v = (t == o) ? 1.f : 0.f;
      else if (t < 20) v = initial_s[b*15 + (t-5)];
      else if (t < 32) v = initial_c[b*30 + d_OIDS[o][t-20]];
      else             v = current_c[b*30 + d_OIDS[o][t-32]];
      xs[t] = v;
    }
    __syncthreads();
    for (int h = t; h < HID; h += 256) {
      float a = eb0[h];
      for (int k = 0; k < 44; ++k) a = fmaf(xs[k], eW0[h*44+k], a);
      h1[h] = fmaxf(a, 0.f);
    }
    __syncthreads();
    for (int h = t; h < HID; h += 256) {
      float a = eb1[h];
      for (int k = 0; k < HID; ++k) a = fmaf(h1[k], eW1[h*512+k], a);
      h2[h] = fmaxf(a, 0.f);
    }
    __syncthreads();
    if (t < 9) {
      float am = bm[t], av = bv[t];
      for (int k = 0; k < HID; ++k) { am = fmaf(h2[k], Wm[t*512+k], am); av = fmaf(h2[k], Wv[t*512+k], av); }
      const int gid = (o*BATCH + b)*9 + t;
      out[OUT_MEANS + gid] = am;
      out[OUT_LV    + gid] = av;
      const float zz = fmaf(eps[gid], expf(0.5f*av), am);
      out[OUT_Z     + gid] = zz;
      ds[5+t] = zz;
    }
    if (t < 41 && (t < 5 || t >= 14)) {
      float v;
      if      (t < 5)  v = (t == o) ? 1.f : 0.f;
      else if (t < 29) v = initial_s[b*15 + (t-14)];
      else             v = initial_c[b*30 + d_OIDS[o][t-29]];
      ds[t] = v;
    }
    __syncthreads();
    for (int h = t; h < HID; h += 256) {
      float a = db0[h];
      for (int k = 0; k < 41; ++k) a = fmaf(ds[k], dW0[h*41+k], a);
      h1[h] = fmaxf(a, 0.f);
    }
    __syncthreads();
    for (int h = t; h < HID; h += 256) {
      float a = db1[h];
      for (int k = 0; k < HID; ++k) a = fmaf(h1[k], dW1[h*512+k], a);
      h2[h] = fmaxf(a, 0.f);
    }
    __syncthreads();
    if (t < 12) {
      float a = db2[t];
      for (int k = 0; k < HID; ++k) a = fmaf(h2[k], dW2[t*512+k], a);
      rec[d_OIDS[o][t]] += 1.f / (1.f + expf(-a));
    }
  }
  __syncthreads();
  if (t < 30) out[b*30+t] = rec[t];
}

extern "C" void kernel_launch(void* const* d_in, const int* in_sizes, int n_in,
                              void* d_out, int out_size, void* d_ws, size_t ws_size,
                              hipStream_t stream)
{
  const float* initial_c = (const float*)d_in[0];
  const float* initial_s = (const float*)d_in[1];
  const float* current_c = (const float*)d_in[2];
  const float* eps       = (const float*)d_in[3];
  const float* eW0 = (const float*)d_in[4];
  const float* eb0 = (const float*)d_in[5];
  const float* eW1 = (const float*)d_in[6];
  const float* eb1 = (const float*)d_in[7];
  const float* Wm  = (const float*)d_in[8];
  const float* bm  = (const float*)d_in[9];
  const float* Wv  = (const float*)d_in[10];
  const float* bv  = (const float*)d_in[11];
  const float* dW0 = (const float*)d_in[12];
  const float* db0 = (const float*)d_in[13];
  const float* dW1 = (const float*)d_in[14];
  const float* db1 = (const float*)d_in[15];
  const float* dW2 = (const float*)d_in[16];
  const float* db2 = (const float*)d_in[17];
  float* out = (float*)d_out;

  if (ws_size >= (size_t)UO_TOTAL * sizeof(unsigned short)) {
    unsigned short* ws = (unsigned short*)d_ws;
    prep_bf16<<<1024, 256, 0, stream>>>(eW0, eW1, Wm, Wv, dW0, dW1, dW2, ws);
    // zero the reconstructed region (atomics accumulate into it)
    hipMemsetAsync(out, 0, (size_t)BATCH * 30 * sizeof(float), stream);
    vae_mfma<<<NOBJ*NBT, 512, 0, stream>>>(initial_c, initial_s, current_c, eps,
                                           eb0, eb1, bm, bv, db0, db1, db2, ws, out);
  } else {
    vae_naive<<<BATCH, 256, 0, stream>>>(initial_c, initial_s, current_c, eps,
                                         eW0, eb0, eW1, eb1, Wm, bm, Wv, bv,
                                         dW0, db0, dW1, db1, dW2, db2, out);
  }
}

// Round 13
// 505.867 us; speedup vs baseline: 1.4919x; 1.4919x over previous
//
#include <hip/hip_runtime.h>
#include <math.h>

// ---------------- problem constants ----------------
#define BATCH 32768
#define HID   512
#define NOBJ  5
#define TM    64            // batch rows per block (MFMA path), 512 threads
#define NBT   (BATCH/TM)    // 512 batch tiles

typedef __attribute__((ext_vector_type(8))) short bf16x8;
typedef __attribute__((ext_vector_type(4))) float f32x4;

__device__ __constant__ int d_OIDS[5][12] = {
  {0,1,2,3, 10,11,12,13,14,18,22,26},
  {0,4,5,6, 10,14,15,16,17,19,23,27},
  {1,4,7,8, 11,15,18,19,20,21,24,28},
  {2,5,7,9, 12,16,20,22,23,24,25,29},
  {3,6,8,9, 13,17,21,25,26,27,28,29}
};

// ---------------- bf16 weight workspace (ushort offsets) ----------------
#define UO_EW0   0                       // [512][64]  (K padded 44->64)
#define UO_EW1   (UO_EW0 + 512*64)       // [512][512]
#define UO_HEADS (UO_EW1 + 512*512)      // [32][512]: rows 0-8 Wm, 16-24 Wv, rest 0
#define UO_DW0   (UO_HEADS + 32*512)     // [512][64]  (K padded 41->64)
#define UO_DW1   (UO_DW0 + 512*64)       // [512][512]
#define UO_DW2   (UO_DW1 + 512*512)      // [16][512]: rows 0-11 dec_W2, rest 0
#define UO_TOTAL (UO_DW2 + 16*512)       // 614400 ushorts = 1.23 MB

// ---------------- output layout (floats) ----------------
#define OUT_MEANS (BATCH*30)
#define OUT_LV    (OUT_MEANS + NOBJ*BATCH*9)
#define OUT_Z     (OUT_LV    + NOBJ*BATCH*9)

// round-to-nearest-even f32 -> bf16 bits
__device__ __forceinline__ unsigned short f2b(float x) {
  unsigned int u = __builtin_bit_cast(unsigned int, x);
  u += 0x7FFFu + ((u >> 16) & 1u);
  return (unsigned short)(u >> 16);
}

// ---------------- prep: convert/pad weights into ws (bf16) ----------------
__global__ void __launch_bounds__(256)
prep_bf16(const float* __restrict__ eW0, const float* __restrict__ eW1,
          const float* __restrict__ Wm,  const float* __restrict__ Wv,
          const float* __restrict__ dW0, const float* __restrict__ dW1,
          const float* __restrict__ dW2, unsigned short* __restrict__ ws)
{
  for (int i = blockIdx.x*blockDim.x + threadIdx.x; i < UO_TOTAL; i += gridDim.x*blockDim.x) {
    float v = 0.f; int j;
    if (i < UO_EW1) {                       // [512][64] <- eW0 [512][44]
      j = i - UO_EW0; int h = j >> 6, k = j & 63;
      if (k < 44) v = eW0[h*44 + k];
    } else if (i < UO_HEADS) {              // [512][512] <- eW1
      j = i - UO_EW1; v = eW1[j];
    } else if (i < UO_DW0) {                // [32][512] heads
      j = i - UO_HEADS; int r = j >> 9, k = j & 511;
      if (r < 9)                  v = Wm[r*512 + k];
      else if (r >= 16 && r < 25) v = Wv[(r-16)*512 + k];
    } else if (i < UO_DW1) {                // [512][64] <- dW0 [512][41]
      j = i - UO_DW0; int h = j >> 6, k = j & 63;
      if (k < 41) v = dW0[h*41 + k];
    } else if (i < UO_DW2) {                // [512][512] <- dW1
      j = i - UO_DW1; v = dW1[j];
    } else {                                // [16][512] <- dW2 [12][512]
      j = i - UO_DW2; int r = j >> 9, k = j & 511;
      if (r < 12) v = dW2[r*512 + k];
    }
    ws[i] = f2b(v);
  }
}

// One dense layer: out[64][512] = relu(in[64][K] * W^T + bias).
// 8 waves, 1M x 8N: wave covers ALL 64 rows x cols [wave*64,+64), acc[4][4]=64.
// B global->registers with even/odd ping-pong; A LDS ping-pong; NO barriers in
// the K-loop. K-PHASE STAGGER: each block starts its K-loop at `off` (wrapping
// mod KT) so same-XCD blocks request DIFFERENT weight lines at any instant --
// de-hotspots the per-XCD L2 broadcast of the shared 1.23MB weight set.
// (K-sum reorder only changes fp32 rounding; threshold has 3.4x margin.)
template<int KT, int ROWW>   // K = KT*32, KT even power of 2
__device__ __forceinline__ void layer_mfma(const unsigned short* sIn,
                                           const unsigned short* __restrict__ Wb,
                                           const float* __restrict__ bias,
                                           unsigned short* sOut,
                                           int wave, int lane, int off)
{
  const int lcol = lane & 15;
  const int kg   = lane >> 4;
  const int lk   = kg * 8;
  const int colbase = wave * 64;
  const int swz = (lcol & 7) << 3;     // rows m*16+lcol: row&7 == lcol&7

  f32x4 acc[4][4];
  #pragma unroll
  for (int n = 0; n < 4; ++n) {
    const float bv = bias[colbase + n*16 + lcol];
    #pragma unroll
    for (int m = 0; m < 4; ++m) acc[m][n] = (f32x4){bv, bv, bv, bv};
  }

  const unsigned short* wpn[4];
  #pragma unroll
  for (int n = 0; n < 4; ++n)
    wpn[n] = Wb + (size_t)(colbase + n*16 + lcol)*(KT*32) + lk;

  bf16x8 a0[4], a1[4], b0[4], b1[4];
  {
    const int p0 = (off    ) & (KT-1);
    const int p1 = (off + 1) & (KT-1);
    #pragma unroll
    for (int n = 0; n < 4; ++n) b0[n] = *(const bf16x8*)(wpn[n] + p0*32);
    #pragma unroll
    for (int n = 0; n < 4; ++n) b1[n] = *(const bf16x8*)(wpn[n] + p1*32);
    const int k0 = p0*32 + lk;
    #pragma unroll
    for (int m = 0; m < 4; ++m)
      a0[m] = *(const bf16x8*)&sIn[(m*16 + lcol)*ROWW + (k0 ^ swz)];
  }

  #pragma unroll 1
  for (int kt = 0; kt < KT; kt += 2) {
    {                                    // prefetch A at phase kt+1
      const int k1 = ((kt + 1 + off) & (KT-1))*32 + lk;
      #pragma unroll
      for (int m = 0; m < 4; ++m)
        a1[m] = *(const bf16x8*)&sIn[(m*16 + lcol)*ROWW + (k1 ^ swz)];
    }
    #pragma unroll
    for (int n = 0; n < 4; ++n)
      #pragma unroll
      for (int m = 0; m < 4; ++m)
        acc[m][n] = __builtin_amdgcn_mfma_f32_16x16x32_bf16(a0[m], b0[n], acc[m][n], 0, 0, 0);
    if (kt + 2 < KT) {                   // prefetch B,A at phase kt+2
      const int p2 = (kt + 2 + off) & (KT-1);
      #pragma unroll
      for (int n = 0; n < 4; ++n) b0[n] = *(const bf16x8*)(wpn[n] + p2*32);
      const int k2 = p2*32 + lk;
      #pragma unroll
      for (int m = 0; m < 4; ++m)
        a0[m] = *(const bf16x8*)&sIn[(m*16 + lcol)*ROWW + (k2 ^ swz)];
    }
    #pragma unroll
    for (int n = 0; n < 4; ++n)
      #pragma unroll
      for (int m = 0; m < 4; ++m)
        acc[m][n] = __builtin_amdgcn_mfma_f32_16x16x32_bf16(a1[m], b1[n], acc[m][n], 0, 0, 0);
    if (kt + 3 < KT) {                   // prefetch B at phase kt+3
      const int p3 = (kt + 3 + off) & (KT-1);
      #pragma unroll
      for (int n = 0; n < 4; ++n) b1[n] = *(const bf16x8*)(wpn[n] + p3*32);
    }
  }

  __syncthreads();   // all reads of sIn done before (possibly aliased) writes
  const int rbase = kg * 4;
  #pragma unroll
  for (int m = 0; m < 4; ++m)
    #pragma unroll
    for (int n = 0; n < 4; ++n) {
      const int col = colbase + n*16 + lcol;
      #pragma unroll
      for (int r = 0; r < 4; ++r) {
        const int row = m*16 + rbase + r;
        sOut[row*512 + (col ^ ((row & 7) << 3))] = f2b(fmaxf(acc[m][n][r], 0.f));
      }
    }
  __syncthreads();
}

// grid = NOBJ * NBT blocks; block = one (object, 64-row batch tile).
__global__ void __launch_bounds__(512, 2)
vae_mfma(const float* __restrict__ initial_c, const float* __restrict__ initial_s,
         const float* __restrict__ current_c, const float* __restrict__ eps,
         const float* __restrict__ enc_b0, const float* __restrict__ enc_b1,
         const float* __restrict__ bm, const float* __restrict__ bv,
         const float* __restrict__ dec_b0, const float* __restrict__ dec_b1,
         const float* __restrict__ dec_b2, const unsigned short* __restrict__ ws,
         float* __restrict__ out)
{
  __shared__ __align__(16) unsigned short s_act[TM*512];   // 64 KB activations
  __shared__ __align__(16) unsigned short s_in[TM*64];     // 8 KB enc/dec input
  __shared__ float s_stage[3*TM*9];                        // 6.9 KB head f32 stage
  // 79 KB; regs ~175/wave -> 1 block/CU, 8 waves (2/SIMD, 256 regs each)

  const int t = threadIdx.x;
  const int wave = t >> 6, lane = t & 63;
  const int lcol = lane & 15, kg = lane >> 4;
  const int lk = kg * 8, rbase = kg * 4;
  const int o     = blockIdx.x / NBT;
  const int bbase = (blockIdx.x % NBT) * TM;
  // K-phase stagger: same-XCD neighbors (blockIdx differing by 8) -> distinct
  const int off16 = (blockIdx.x >> 3) & 15;
  const int off2  = (blockIdx.x >> 3) & 1;

  // ---- encoder input [64][64]: [oh 0-4 | s 5-19 | gi 20-31 | gc 32-43 | 0] ----
  for (int s = t; s < TM*64; s += 512) {
    const int row = s >> 6, col = s & 63;
    float v = 0.f;
    if (col < 5)       v = (col == o) ? 1.f : 0.f;
    else if (col < 20) v = initial_s[(bbase+row)*15 + col - 5];
    else if (col < 32) v = initial_c[(bbase+row)*30 + d_OIDS[o][col-20]];
    else if (col < 44) v = current_c[(bbase+row)*30 + d_OIDS[o][col-32]];
    s_in[row*64 + (col ^ ((row & 7) << 3))] = f2b(v);
  }
  __syncthreads();

  layer_mfma<2, 64>  (s_in,  ws + UO_EW0, enc_b0, s_act, wave, lane, off2);   // h1
  layer_mfma<16, 512>(s_act, ws + UO_EW1, enc_b1, s_act, wave, lane, off16);  // h2

  // ---- heads: means / log_var / z (waves 0-3 own M-tiles [wave*16,+16)) ----
  {
    // decoder input (non-z cols): [oh 0-4 | z 5-13 | s 14-28 | gi 29-40 | 0]
    for (int s = t; s < TM*64; s += 512) {
      const int row = s >> 6, col = s & 63;
      if (col >= 5 && col < 14) continue;
      float v = 0.f;
      if (col < 5)       v = (col == o) ? 1.f : 0.f;
      else if (col < 29) v = initial_s[(bbase+row)*15 + col - 14];
      else if (col < 41) v = initial_c[(bbase+row)*30 + d_OIDS[o][col-29]];
      s_in[row*64 + (col ^ ((row & 7) << 3))] = f2b(v);
    }
    f32x4 am, av;
    if (wave < 4) {
      const float bmv = (lcol < 9) ? bm[lcol] : 0.f;
      const float bvv = (lcol < 9) ? bv[lcol] : 0.f;
      am = (f32x4){bmv, bmv, bmv, bmv};
      av = (f32x4){bvv, bvv, bvv, bvv};
      const unsigned short* hpM = ws + UO_HEADS + lcol*512 + lk;
      const unsigned short* hpV = hpM + 16*512;
      const int hrow = wave*16 + lcol;
      const int p0 = off16;
      bf16x8 m0 = *(const bf16x8*)(hpM + p0*32);
      bf16x8 v0 = *(const bf16x8*)(hpV + p0*32);
      #pragma unroll 1
      for (int kt = 0; kt < 16; ++kt) {
        bf16x8 m1 = m0, v1 = v0;
        if (kt + 1 < 16) {               // register ping-pong prefetch
          const int p1 = (kt + 1 + off16) & 15;
          m1 = *(const bf16x8*)(hpM + p1*32);
          v1 = *(const bf16x8*)(hpV + p1*32);
        }
        const int k0 = ((kt + off16) & 15)*32 + lk;
        bf16x8 a = *(const bf16x8*)&s_act[hrow*512 + (k0 ^ ((lcol & 7) << 3))];
        am = __builtin_amdgcn_mfma_f32_16x16x32_bf16(a, m0, am, 0, 0, 0);
        av = __builtin_amdgcn_mfma_f32_16x16x32_bf16(a, v0, av, 0, 0, 0);
        m0 = m1; v0 = v1;
      }
    }
    __syncthreads();   // all head reads of h2 done
    if (wave < 4 && lcol < 9) {
      #pragma unroll
      for (int r = 0; r < 4; ++r) {
        const int row = wave*16 + rbase + r;
        const int gid = (o*BATCH + bbase + row)*9 + lcol;
        const float m_ = am[r], v_ = av[r];
        const float zz = fmaf(eps[gid], expf(0.5f*v_), m_);
        s_stage[        row*9 + lcol] = m_;
        s_stage[576 +   row*9 + lcol] = v_;
        s_stage[1152 +  row*9 + lcol] = zz;
        s_in[row*64 + ((5 + lcol) ^ ((row & 7) << 3))] = f2b(zz);
      }
    }
    __syncthreads();
    // coalesced nontemporal head-output writes (contiguous 2.3 KB each)
    const int ob_m = OUT_MEANS + (o*BATCH + bbase)*9;
    const int ob_v = OUT_LV    + (o*BATCH + bbase)*9;
    const int ob_z = OUT_Z     + (o*BATCH + bbase)*9;
    for (int i = t; i < TM*9; i += 512) {
      __builtin_nontemporal_store(s_stage[i],        &out[ob_m + i]);
      __builtin_nontemporal_store(s_stage[576 + i],  &out[ob_v + i]);
      __builtin_nontemporal_store(s_stage[1152 + i], &out[ob_z + i]);
    }
  }

  layer_mfma<2, 64>  (s_in,  ws + UO_DW0, dec_b0, s_act, wave, lane, off2);   // g1
  layer_mfma<16, 512>(s_act, ws + UO_DW1, dec_b1, s_act, wave, lane, off16);  // g2

  // ---- dec head: sigmoid + atomic scatter (exactly 2 commutative adds/elem) ----
  if (wave < 4) {
    const float b2 = (lcol < 12) ? dec_b2[lcol] : 0.f;
    f32x4 acc = (f32x4){b2, b2, b2, b2};
    const unsigned short* wp = ws + UO_DW2 + lcol*512 + lk;
    const int hrow = wave*16 + lcol;
    bf16x8 b0 = *(const bf16x8*)(wp + off16*32);
    #pragma unroll 1
    for (int kt = 0; kt < 16; ++kt) {
      bf16x8 b1 = b0;
      if (kt + 1 < 16) b1 = *(const bf16x8*)(wp + ((kt + 1 + off16) & 15)*32);
      const int k0 = ((kt + off16) & 15)*32 + lk;
      bf16x8 a = *(const bf16x8*)&s_act[hrow*512 + (k0 ^ ((lcol & 7) << 3))];
      acc = __builtin_amdgcn_mfma_f32_16x16x32_bf16(a, b0, acc, 0, 0, 0);
      b0 = b1;
    }
    if (lcol < 12) {
      const int c30 = d_OIDS[o][lcol];
      #pragma unroll
      for (int r = 0; r < 4; ++r) {
        const int row = wave*16 + rbase + r;
        atomicAdd(&out[(bbase + row)*30 + c30], 1.f / (1.f + expf(-acc[r])));
      }
    }
  }
}

// ---------------- fallback (ws too small): correct but slow fp32 ----------------
__global__ void __launch_bounds__(256)
vae_naive(const float* __restrict__ initial_c, const float* __restrict__ initial_s,
          const float* __restrict__ current_c, const float* __restrict__ eps,
          const float* eW0, const float* eb0, const float* eW1, const float* eb1,
          const float* Wm, const float* bm, const float* Wv, const float* bv,
          const float* dW0, const float* db0, const float* dW1, const float* db1,
          const float* dW2, const float* db2, float* out)
{
  __shared__ float xs[44], ds[41], h1[HID], h2[HID], rec[30];
  const int b = blockIdx.x, t = threadIdx.x;
  if (t < 30) rec[t] = 0.f;
  for (int o = 0; o < NOBJ; ++o) {
    __syncthreads();
    if (t < 44) {
      float v;
      if      (t < 5)  v = (t == o) ? 1.f : 0.f;
      else if (t < 20) v = initial_s[b*15 + (t-5)];
      else if (t < 32) v = initial_c[b*30 + d_OIDS[o][t-20]];
      else             v = current_c[b*30 + d_OIDS[o][t-32]];
      xs[t] = v;
    }
    __syncthreads();
    for (int h = t; h < HID; h += 256) {
      float a = eb0[h];
      for (int k = 0; k < 44; ++k) a = fmaf(xs[k], eW0[h*44+k], a);
      h1[h] = fmaxf(a, 0.f);
    }
    __syncthreads();
    for (int h = t; h < HID; h += 256) {
      float a = eb1[h];
      for (int k = 0; k < HID; ++k) a = fmaf(h1[k], eW1[h*512+k], a);
      h2[h] = fmaxf(a, 0.f);
    }
    __syncthreads();
    if (t < 9) {
      float am = bm[t], av = bv[t];
      for (int k = 0; k < HID; ++k) { am = fmaf(h2[k], Wm[t*512+k], am); av = fmaf(h2[k], Wv[t*512+k], av); }
      const int gid = (o*BATCH + b)*9 + t;
      out[OUT_MEANS + gid] = am;
      out[OUT_LV    + gid] = av;
      const float zz = fmaf(eps[gid], expf(0.5f*av), am);
      out[OUT_Z     + gid] = zz;
      ds[5+t] = zz;
    }
    if (t < 41 && (t < 5 || t >= 14)) {
      float v;
      if      (t < 5)  v = (t == o) ? 1.f : 0.f;
      else if (t < 29) v = initial_s[b*15 + (t-14)];
      else             v = initial_c[b*30 + d_OIDS[o][t-29]];
      ds[t] = v;
    }
    __syncthreads();
    for (int h = t; h < HID; h += 256) {
      float a = db0[h];
      for (int k = 0; k < 41; ++k) a = fmaf(ds[k], dW0[h*41+k], a);
      h1[h] = fmaxf(a, 0.f);
    }
    __syncthreads();
    for (int h = t; h < HID; h += 256) {
      float a = db1[h];
      for (int k = 0; k < HID; ++k) a = fmaf(h1[k], dW1[h*512+k], a);
      h2[h] = fmaxf(a, 0.f);
    }
    __syncthreads();
    if (t < 12) {
      float a = db2[t];
      for (int k = 0; k < HID; ++k) a = fmaf(h2[k], dW2[t*512+k], a);
      rec[d_OIDS[o][t]] += 1.f / (1.f + expf(-a));
    }
  }
  __syncthreads();
  if (t < 30) out[b*30+t] = rec[t];
}

extern "C" void kernel_launch(void* const* d_in, const int* in_sizes, int n_in,
                              void* d_out, int out_size, void* d_ws, size_t ws_size,
                              hipStream_t stream)
{
  const float* initial_c = (const float*)d_in[0];
  const float* initial_s = (const float*)d_in[1];
  const float* current_c = (const float*)d_in[2];
  const float* eps       = (const float*)d_in[3];
  const float* eW0 = (const float*)d_in[4];
  const float* eb0 = (const float*)d_in[5];
  const float* eW1 = (const float*)d_in[6];
  const float* eb1 = (const float*)d_in[7];
  const float* Wm  = (const float*)d_in[8];
  const float* bm  = (const float*)d_in[9];
  const float* Wv  = (const float*)d_in[10];
  const float* bv  = (const float*)d_in[11];
  const float* dW0 = (const float*)d_in[12];
  const float* db0 = (const float*)d_in[13];
  const float* dW1 = (const float*)d_in[14];
  const float* db1 = (const float*)d_in[15];
  const float* dW2 = (const float*)d_in[16];
  const float* db2 = (const float*)d_in[17];
  float* out = (float*)d_out;

  if (ws_size >= (size_t)UO_TOTAL * sizeof(unsigned short)) {
    unsigned short* ws = (unsigned short*)d_ws;
    prep_bf16<<<1024, 256, 0, stream>>>(eW0, eW1, Wm, Wv, dW0, dW1, dW2, ws);
    // zero the reconstructed region (atomics accumulate into it)
    hipMemsetAsync(out, 0, (size_t)BATCH * 30 * sizeof(float), stream);
    vae_mfma<<<NOBJ*NBT, 512, 0, stream>>>(initial_c, initial_s, current_c, eps,
                                           eb0, eb1, bm, bv, db0, db1, db2, ws, out);
  } else {
    vae_naive<<<BATCH, 256, 0, stream>>>(initial_c, initial_s, current_c, eps,
                                         eW0, eb0, eW1, eb1, Wm, bm, Wv, bv,
                                         dW0, db0, dW1, db1, dW2, db2, out);
  }
}